// Round 4
// baseline (930.681 us; speedup 1.0000x reference)
//
#include <hip/hip_runtime.h>

#define BB 64
#define LL 512
#define DD 1024
#define CC 131
#define CP 132
#define START_I 129
#define STOP_I 130
#define NEGV -10000.0f

// Raw workgroup barrier: makes LDS writes visible without draining vmcnt
// (so global stores/prefetches stay in flight across steps).
__device__ __forceinline__ void lds_barrier() {
    asm volatile("s_waitcnt lgkmcnt(0)" ::: "memory");
    __builtin_amdgcn_s_barrier();
    __builtin_amdgcn_sched_barrier(0);
}

// ---------------- Kernel 1: feats[m][c] = dot(x[m,:], W[c,:]) + b[c] ----------------
#define GM 128
#define GK 32
#define LSTR 36

__global__ __launch_bounds__(256, 1) void gemm_feats(
    const float* __restrict__ x, const float* __restrict__ W,
    const float* __restrict__ bias, float* __restrict__ feats)
{
    __shared__ float xs[GM * LSTR];   // [m][k]
    __shared__ float ws[CP * LSTR];   // [j][k]

    const int tid = threadIdx.x;
    const int m0 = blockIdx.x * GM;
    const int tm = tid & 15;          // rows tm + 16r
    const int tj = (tid >> 4) & 15;   // cols tj + 16c
    const bool tail = (tj < 3);
    const int tjt = (tj < 3) ? tj : 2;

    float acc[8][8];
    float acct[8];
#pragma unroll
    for (int r = 0; r < 8; ++r) {
        acct[r] = 0.f;
#pragma unroll
        for (int c = 0; c < 8; ++c) acc[r][c] = 0.f;
    }

    for (int kc = 0; kc < DD / GK; ++kc) {
        const int k0 = kc * GK;
        if (kc) __syncthreads();
#pragma unroll
        for (int q = 0; q < 4; ++q) {
            int lin = tid + q * 256;
            int m = lin >> 3, c4 = lin & 7;
            float4 v = *(const float4*)&x[(size_t)(m0 + m) * DD + k0 + c4 * 4];
            *(float4*)&xs[m * LSTR + c4 * 4] = v;
        }
#pragma unroll
        for (int q = 0; q < 5; ++q) {
            int lin = tid + q * 256;
            if (lin < CC * 8) {
                int r = lin >> 3, c4 = lin & 7;
                float4 v = *(const float4*)&W[(size_t)r * DD + k0 + c4 * 4];
                *(float4*)&ws[r * LSTR + c4 * 4] = v;
            }
        }
        __syncthreads();

#pragma unroll
        for (int k4 = 0; k4 < 8; ++k4) {
            float4 xr[8], wr[8], wt;
#pragma unroll
            for (int r = 0; r < 8; ++r)
                xr[r] = *(const float4*)&xs[(tm + 16 * r) * LSTR + k4 * 4];
#pragma unroll
            for (int c = 0; c < 8; ++c)
                wr[c] = *(const float4*)&ws[(tj + 16 * c) * LSTR + k4 * 4];
            wt = *(const float4*)&ws[(128 + tjt) * LSTR + k4 * 4];
#pragma unroll
            for (int r = 0; r < 8; ++r) {
#pragma unroll
                for (int c = 0; c < 8; ++c) {
                    acc[r][c] = fmaf(xr[r].x, wr[c].x, acc[r][c]);
                    acc[r][c] = fmaf(xr[r].y, wr[c].y, acc[r][c]);
                    acc[r][c] = fmaf(xr[r].z, wr[c].z, acc[r][c]);
                    acc[r][c] = fmaf(xr[r].w, wr[c].w, acc[r][c]);
                }
                acct[r] = fmaf(xr[r].x, wt.x, acct[r]);
                acct[r] = fmaf(xr[r].y, wt.y, acct[r]);
                acct[r] = fmaf(xr[r].z, wt.z, acct[r]);
                acct[r] = fmaf(xr[r].w, wt.w, acct[r]);
            }
        }
    }

#pragma unroll
    for (int c = 0; c < 8; ++c) {
        int j = tj + 16 * c;
        float bv = bias[j];
#pragma unroll
        for (int r = 0; r < 8; ++r)
            feats[(size_t)(m0 + tm + 16 * r) * CP + j] = acc[r][c] + bv;
    }
    if (tail) {
        int j = 128 + tj;
        float bv = bias[j];
#pragma unroll
        for (int r = 0; r < 8; ++r)
            feats[(size_t)(m0 + tm + 16 * r) * CP + j] = acct[r] + bv;
    }
}

// ---------------- Kernel 2: Viterbi forward, 4-wave half-row split ----------------
// 64 blocks x 256 threads. Wave w: i-half = w>>1, columns (w&1)*64 + lane.
// Each lane keeps HALF a T-row (68 floats -> stays in VGPRs, unlike the 132-float
// full row which the allocator sank to per-step global reloads).
__global__ __launch_bounds__(256, 1) void viterbi_fwd(
    const float* __restrict__ feats, const float* __restrict__ mask,
    const float* __restrict__ trans, float* __restrict__ hist)
{
    const int b = blockIdx.x;
    const int tid = threadIdx.x;
    const int wave = tid >> 6, lane = tid & 63;
    const int ihalf = wave >> 1;               // 0: i in [0,64), 1: i in [64,132)
    const int col = (wave & 1) * 64 + lane;    // 0..127 (always valid)
    const bool comb = (wave < 2);              // combine waves
    const bool w0x = (wave == 0 && lane < 3);  // extra-col writer lanes

    __shared__ float sbuf[2][192];             // [131 cols][pad 132..191 = NEGV]
    __shared__ float pbuf[2][132];             // per-half partial maxes

    // ---- T main half-slice: 17 float4 = 68 regs
    float4 T0[17];
    {
        const float* trow = trans + (size_t)col * CC;
        if (ihalf == 0) {
#pragma unroll
            for (int q = 0; q < 16; ++q) {
                T0[q].x = trow[q * 4 + 0]; T0[q].y = trow[q * 4 + 1];
                T0[q].z = trow[q * 4 + 2]; T0[q].w = trow[q * 4 + 3];
            }
            T0[16] = make_float4(NEGV, NEGV, NEGV, NEGV);   // pairs with s[64..67]; -1e4 can't win
        } else {
#pragma unroll
            for (int q = 0; q < 16; ++q) {
                T0[q].x = trow[64 + q * 4 + 0]; T0[q].y = trow[64 + q * 4 + 1];
                T0[q].z = trow[64 + q * 4 + 2]; T0[q].w = trow[64 + q * 4 + 3];
            }
            T0[16].x = trow[128]; T0[16].y = trow[129]; T0[16].z = trow[130];
            T0[16].w = NEGV;                                 // pad i=131
        }
    }

    // ---- extra-col (128..130) butterfly T scalars
    float ex_a0 = NEGV, ex_a1 = NEGV, ex_a2 = NEGV;
    float ex_b0 = NEGV, ex_b1 = NEGV, ex_b2 = NEGV;
    if (wave == 0) {            // i = lane
        ex_a0 = trans[(size_t)128 * CC + lane];
        ex_a1 = trans[(size_t)129 * CC + lane];
        ex_a2 = trans[(size_t)130 * CC + lane];
    } else if (wave == 2) {     // i = 64+lane, plus i = 128+lane for lane<3
        ex_a0 = trans[(size_t)128 * CC + 64 + lane];
        ex_a1 = trans[(size_t)129 * CC + 64 + lane];
        ex_a2 = trans[(size_t)130 * CC + 64 + lane];
        if (lane < 3) {
            ex_b0 = trans[(size_t)128 * CC + 128 + lane];
            ex_b1 = trans[(size_t)129 * CC + 128 + lane];
            ex_b2 = trans[(size_t)130 * CC + 128 + lane];
        }
    }

    // ---- init sbuf (both buffers fully NEGV; [0][START]=0; pads persist)
    for (int q = tid; q < 2 * 192; q += 256) {
        int bufi = q / 192, idx = q - bufi * 192;
        sbuf[bufi][idx] = (bufi == 0 && idx == START_I) ? 0.f : NEGV;
    }
    __syncthreads();

    const float* fb = feats + (size_t)b * LL * CP;
    const float* mb = mask + (size_t)b * LL;
    float* hb = hist + (size_t)b * LL * CP;

    float s_reg = NEGV;                        // cols 0..127 never START
    float sx_reg = (128 + lane == START_I) ? 0.f : NEGV;   // for w0x lanes

    float fv0 = 0.f, fv1 = 0.f, mv0 = 1.f, mv1 = 1.f, fx0 = 0.f, fx1 = 0.f;
    if (comb) {
        fv0 = fb[col]; fv1 = fb[CP + col];
        mv0 = mb[0]; mv1 = mb[1];
    }
    if (w0x) { fx0 = fb[128 + lane]; fx1 = fb[CP + 128 + lane]; }

    int cur = 0;
    float ns_p = 0.f, nsx_p = 0.f;

    for (int t = 0; t < LL; ++t) {
        // deferred hist stores from step t-1 (stay in flight across lgkm barriers)
        if (t > 0) {
            if (comb) hb[(size_t)(t - 1) * CP + col] = ns_p;
            if (w0x)  hb[(size_t)(t - 1) * CP + 128 + lane] = nsx_p;
        }
        // prefetch t+2
        float fv2 = 0.f, mv2 = 1.f, fx2 = 0.f;
        if (t + 2 < LL) {
            if (comb) { fv2 = fb[(size_t)(t + 2) * CP + col]; mv2 = mb[t + 2]; }
            if (w0x)  { fx2 = fb[(size_t)(t + 2) * CP + 128 + lane]; }
        }

        // ---- phase 1: partial max over my i-half (broadcast b128 reads)
        const float4* s4 = (const float4*)(&sbuf[cur][0] + ihalf * 64);
        float mx0 = -3.0e38f, mx1 = -3.0e38f;
#pragma unroll
        for (int q = 0; q < 17; ++q) {
            float4 sv = s4[q];
            float v0 = sv.x + T0[q].x, v1 = sv.y + T0[q].y;
            float v2 = sv.z + T0[q].z, v3 = sv.w + T0[q].w;
            mx0 = fmaxf(mx0, fmaxf(v0, v1));
            mx1 = fmaxf(mx1, fmaxf(v2, v3));
        }
        float p = fmaxf(mx0, mx1);

        // ---- extras: cols 128..130 via shuffle butterfly (waves 0 and 2)
        float c0 = -3.0e38f, c1 = -3.0e38f, c2 = -3.0e38f;
        if (wave == 0) {
            float s0 = sbuf[cur][lane];
            c0 = s0 + ex_a0; c1 = s0 + ex_a1; c2 = s0 + ex_a2;
        } else if (wave == 2) {
            float sA = sbuf[cur][64 + lane];
            float sB = sbuf[cur][128 + lane];   // pad lanes read NEGV
            c0 = fmaxf(sA + ex_a0, sB + ex_b0);
            c1 = fmaxf(sA + ex_a1, sB + ex_b1);
            c2 = fmaxf(sA + ex_a2, sB + ex_b2);
        }
        if (wave == 0 || wave == 2) {
#pragma unroll
            for (int off = 1; off < 64; off <<= 1) {
                c0 = fmaxf(c0, __shfl_xor(c0, off, 64));
                c1 = fmaxf(c1, __shfl_xor(c1, off, 64));
                c2 = fmaxf(c2, __shfl_xor(c2, off, 64));
            }
            pbuf[ihalf][col] = p;               // main partial
            if (lane < 3) {
                float cw = (lane == 0) ? c0 : ((lane == 1) ? c1 : c2);
                pbuf[ihalf][128 + lane] = cw;
            }
        } else {
            pbuf[ihalf][col] = p;
        }

        lds_barrier();   // partials + sbuf[cur] reads complete

        // ---- phase 2: combine halves, blend, publish (waves 0,1)
        if (comb) {
            float best = fmaxf(pbuf[0][col], pbuf[1][col]);
            float ns = (mv0 != 0.f) ? (best + fv0) : s_reg;
            s_reg = ns;
            sbuf[cur ^ 1][col] = ns;
            ns_p = ns;
            if (w0x) {
                float bx = fmaxf(pbuf[0][128 + lane], pbuf[1][128 + lane]);
                float nsx = (mv0 != 0.f) ? (bx + fx0) : sx_reg;
                sx_reg = nsx;
                sbuf[cur ^ 1][128 + lane] = nsx;
                nsx_p = nsx;
            }
        }

        lds_barrier();   // sbuf[cur^1] published

        fv0 = fv1; fv1 = fv2; mv0 = mv1; mv1 = mv2; fx0 = fx1; fx1 = fx2;
        cur ^= 1;
    }
    if (comb) hb[(size_t)(LL - 1) * CP + col] = ns_p;
    if (w0x)  hb[(size_t)(LL - 1) * CP + 128 + lane] = nsx_p;
}

// ---------------- Kernel 3: backpointer matrix (unchanged) ----------------
__global__ __launch_bounds__(256, 4) void bp_kernel(
    const float* __restrict__ hist, const float* __restrict__ trans,
    unsigned char* __restrict__ bp)
{
    const int b  = blockIdx.x / 5;
    const int jc = blockIdx.x % 5;
    const int tc = blockIdx.y;
    const int tid = threadIdx.x;
    const int j0 = jc * 32;

    __shared__ float Ts[32][136];
    __shared__ float hs[8][132];

    for (int q = 0; q < 17; ++q) {
        int lin = tid + q * 256;
        if (lin < 32 * CC) {
            int r = lin / CC, i = lin - r * CC;
            if (j0 + r < CC) Ts[r][i] = trans[(size_t)(j0 + r) * CC + i];
        }
    }
    {
        const float4* src = (const float4*)(hist + ((size_t)b * LL + tc * 8) * CP);
#pragma unroll
        for (int q = 0; q < 2; ++q) {
            int lin = tid + q * 256;
            if (lin < (8 * CP) / 4) ((float4*)hs)[lin] = src[lin];
        }
    }
    __syncthreads();

    const int jl = tid & 31;
    const int tt = tid >> 5;
    const int j = j0 + jl;
    const int t = tc * 8 + tt + 1;
    if (j >= CC || t >= LL) return;

    float best; int idx;
    {
        float4 tv = *(const float4*)&Ts[jl][128];
        float4 hv = *(const float4*)&hs[tt][128];
        best = hv.z + tv.z; idx = 130;
        float v;
        v = hv.y + tv.y; if (v >= best) { best = v; idx = 129; }
        v = hv.x + tv.x; if (v >= best) { best = v; idx = 128; }
    }
#pragma unroll
    for (int i4 = 31; i4 >= 0; --i4) {
        float4 tv = *(const float4*)&Ts[jl][i4 * 4];
        float4 hv = *(const float4*)&hs[tt][i4 * 4];
        float v;
        v = hv.w + tv.w; if (v >= best) { best = v; idx = i4 * 4 + 3; }
        v = hv.z + tv.z; if (v >= best) { best = v; idx = i4 * 4 + 2; }
        v = hv.y + tv.y; if (v >= best) { best = v; idx = i4 * 4 + 1; }
        v = hv.x + tv.x; if (v >= best) { best = v; idx = i4 * 4 + 0; }
    }
    bp[((size_t)b * LL + t) * CP + j] = (unsigned char)idx;
}

// ---------------- Kernel 4: final argmax + LDS-streamed u8 backtrack (unchanged) ----------------
__global__ __launch_bounds__(64, 1) void viterbi_btr(
    const float* __restrict__ hist, const float* __restrict__ trans,
    const unsigned char* __restrict__ bp,
    float* __restrict__ out_score, float* __restrict__ out_path)
{
    const int b = blockIdx.x;
    const int lane = threadIdx.x;
    const float* hb = hist + ((size_t)b * LL + (LL - 1)) * CP;
    const float* ts = trans + (size_t)STOP_I * CC;

    float v0 = hb[lane] + ts[lane];
    float v1 = hb[lane + 64] + ts[lane + 64];
    float v2 = (lane < 3) ? (hb[lane + 128] + ts[lane + 128]) : -3.0e38f;

    float best = v0; int idx = lane;
    if (v1 > best) { best = v1; idx = lane + 64; }
    if (v2 > best) { best = v2; idx = lane + 128; }
#pragma unroll
    for (int off = 32; off >= 1; off >>= 1) {
        float ob = __shfl_xor(best, off, 64);
        int   oi = __shfl_xor(idx, off, 64);
        if (ob > best || (ob == best && oi < idx)) { best = ob; idx = oi; }
    }

    float* op = out_path + (size_t)b * LL;
    if (lane == 0) {
        out_score[b] = best;
        op[LL - 1] = (float)idx;
    }
    int tag = idx;

    __shared__ unsigned char buf[2][1088];
    const unsigned char* bpb = bp + (size_t)b * LL * CP;

    {
        const unsigned int* src = (const unsigned int*)(bpb + (size_t)504 * CP);
        unsigned int* dst = (unsigned int*)buf[1];
#pragma unroll
        for (int q = 0; q < 5; ++q) {
            int lin = lane + q * 64;
            if (lin < 264) dst[lin] = src[lin];
        }
    }
    lds_barrier();

    int cur = 1;
    for (int k = 63; k >= 0; --k) {
        unsigned int r0 = 0, r1 = 0, r2 = 0, r3 = 0, r4 = 0;
        if (k > 0) {
            const unsigned int* src = (const unsigned int*)(bpb + (size_t)(k - 1) * 8 * CP);
            r0 = src[lane];
            r1 = src[lane + 64];
            r2 = src[lane + 128];
            r3 = src[lane + 192];
            if (lane < 8) r4 = src[lane + 256];
        }
        const unsigned char* cb = buf[cur];
#pragma unroll
        for (int s = 7; s >= 0; --s) {
            int t = k * 8 + s;
            if (t >= 1) {
                tag = cb[s * CP + tag];
                if (lane == 0) op[t - 1] = (float)tag;
            }
        }
        if (k > 0) {
            unsigned int* dst = (unsigned int*)buf[cur ^ 1];
            dst[lane] = r0;
            dst[lane + 64] = r1;
            dst[lane + 128] = r2;
            dst[lane + 192] = r3;
            if (lane < 8) dst[lane + 256] = r4;
            lds_barrier();
        }
        cur ^= 1;
    }
}

extern "C" void kernel_launch(void* const* d_in, const int* in_sizes, int n_in,
                              void* d_out, int out_size, void* d_ws, size_t ws_size,
                              hipStream_t stream)
{
    const float* x     = (const float*)d_in[0];
    const float* mask  = (const float*)d_in[1];
    const float* W     = (const float*)d_in[2];
    const float* bias  = (const float*)d_in[3];
    const float* trans = (const float*)d_in[4];

    float* feats = (float*)d_ws;
    float* hist  = feats + (size_t)BB * LL * CP;
    unsigned char* bp = (unsigned char*)(hist + (size_t)BB * LL * CP);
    float* out_score = (float*)d_out;
    float* out_path  = out_score + BB;

    hipLaunchKernelGGL(gemm_feats, dim3((BB * LL) / GM), dim3(256), 0, stream, x, W, bias, feats);
    hipLaunchKernelGGL(viterbi_fwd, dim3(BB), dim3(256), 0, stream, feats, mask, trans, hist);
    hipLaunchKernelGGL(bp_kernel, dim3(BB * 5, 64), dim3(256), 0, stream, hist, trans, bp);
    hipLaunchKernelGGL(viterbi_btr, dim3(BB), dim3(64), 0, stream, hist, trans, bp, out_score, out_path);
}

// Round 5
// 886.392 us; speedup vs baseline: 1.0500x; 1.0500x over previous
//
#include <hip/hip_runtime.h>

#define BB 64
#define LL 512
#define DD 1024
#define CC 131
#define CP 132
#define START_I 129
#define STOP_I 130
#define NEGV -10000.0f

// Raw workgroup barrier: makes LDS writes visible without draining vmcnt
// (so global stores/prefetches stay in flight across steps).
__device__ __forceinline__ void lds_barrier() {
    asm volatile("s_waitcnt lgkmcnt(0)" ::: "memory");
    __builtin_amdgcn_s_barrier();
    __builtin_amdgcn_sched_barrier(0);
}

// ---------------- Kernel 1: feats[m][c] = dot(x[m,:], W[c,:]) + b[c] ----------------
#define GM 128
#define GK 32
#define LSTR 36

__global__ __launch_bounds__(256, 1) void gemm_feats(
    const float* __restrict__ x, const float* __restrict__ W,
    const float* __restrict__ bias, float* __restrict__ feats)
{
    __shared__ float xs[GM * LSTR];   // [m][k]
    __shared__ float ws[CP * LSTR];   // [j][k]

    const int tid = threadIdx.x;
    const int m0 = blockIdx.x * GM;
    const int tm = tid & 15;          // rows tm + 16r
    const int tj = (tid >> 4) & 15;   // cols tj + 16c
    const bool tail = (tj < 3);
    const int tjt = (tj < 3) ? tj : 2;

    float acc[8][8];
    float acct[8];
#pragma unroll
    for (int r = 0; r < 8; ++r) {
        acct[r] = 0.f;
#pragma unroll
        for (int c = 0; c < 8; ++c) acc[r][c] = 0.f;
    }

    for (int kc = 0; kc < DD / GK; ++kc) {
        const int k0 = kc * GK;
        if (kc) __syncthreads();
#pragma unroll
        for (int q = 0; q < 4; ++q) {
            int lin = tid + q * 256;
            int m = lin >> 3, c4 = lin & 7;
            float4 v = *(const float4*)&x[(size_t)(m0 + m) * DD + k0 + c4 * 4];
            *(float4*)&xs[m * LSTR + c4 * 4] = v;
        }
#pragma unroll
        for (int q = 0; q < 5; ++q) {
            int lin = tid + q * 256;
            if (lin < CC * 8) {
                int r = lin >> 3, c4 = lin & 7;
                float4 v = *(const float4*)&W[(size_t)r * DD + k0 + c4 * 4];
                *(float4*)&ws[r * LSTR + c4 * 4] = v;
            }
        }
        __syncthreads();

#pragma unroll
        for (int k4 = 0; k4 < 8; ++k4) {
            float4 xr[8], wr[8], wt;
#pragma unroll
            for (int r = 0; r < 8; ++r)
                xr[r] = *(const float4*)&xs[(tm + 16 * r) * LSTR + k4 * 4];
#pragma unroll
            for (int c = 0; c < 8; ++c)
                wr[c] = *(const float4*)&ws[(tj + 16 * c) * LSTR + k4 * 4];
            wt = *(const float4*)&ws[(128 + tjt) * LSTR + k4 * 4];
#pragma unroll
            for (int r = 0; r < 8; ++r) {
#pragma unroll
                for (int c = 0; c < 8; ++c) {
                    acc[r][c] = fmaf(xr[r].x, wr[c].x, acc[r][c]);
                    acc[r][c] = fmaf(xr[r].y, wr[c].y, acc[r][c]);
                    acc[r][c] = fmaf(xr[r].z, wr[c].z, acc[r][c]);
                    acc[r][c] = fmaf(xr[r].w, wr[c].w, acc[r][c]);
                }
                acct[r] = fmaf(xr[r].x, wt.x, acct[r]);
                acct[r] = fmaf(xr[r].y, wt.y, acct[r]);
                acct[r] = fmaf(xr[r].z, wt.z, acct[r]);
                acct[r] = fmaf(xr[r].w, wt.w, acct[r]);
            }
        }
    }

#pragma unroll
    for (int c = 0; c < 8; ++c) {
        int j = tj + 16 * c;
        float bv = bias[j];
#pragma unroll
        for (int r = 0; r < 8; ++r)
            feats[(size_t)(m0 + tm + 16 * r) * CP + j] = acc[r][c] + bv;
    }
    if (tail) {
        int j = 128 + tj;
        float bv = bias[j];
#pragma unroll
        for (int r = 0; r < 8; ++r)
            feats[(size_t)(m0 + tm + 16 * r) * CP + j] = acct[r] + bv;
    }
}

// ---- load one i-half of a T row into 17 float4 (fully unrolled, const-indexed) ----
__device__ __forceinline__ void load_T_half(float4* T, const float* __restrict__ trans,
                                            int row, int h) {
    const float* tr = trans + (size_t)row * CC + h * 64;
    if (h == 0) {
#pragma unroll
        for (int q = 0; q < 16; ++q) {
            T[q].x = tr[4 * q + 0]; T[q].y = tr[4 * q + 1];
            T[q].z = tr[4 * q + 2]; T[q].w = tr[4 * q + 3];
        }
        T[16] = make_float4(NEGV, NEGV, NEGV, NEGV);   // pairs with s[64..67]; -1e4 never wins
    } else {
#pragma unroll
        for (int q = 0; q < 16; ++q) {
            T[q].x = tr[4 * q + 0]; T[q].y = tr[4 * q + 1];
            T[q].z = tr[4 * q + 2]; T[q].w = tr[4 * q + 3];
        }
        T[16].x = tr[64]; T[16].y = tr[65]; T[16].z = tr[66];   // i = 128..130
        T[16].w = NEGV;                                          // i = 131 pad
    }
}

// ---------------- Kernel 2: Viterbi forward, pair-split (1 shfl + 1 barrier / step) ------
// 64 blocks x 256 threads. tid -> (column j = tid>>1, i-half h = tid&1). Each lane holds
// a 68-float T-half in VGPRs, computes a partial max, combines with partner via
// __shfl_xor(p,1); even lane blends + publishes to double-buffered sbuf.
// Columns 128..130 are dual-duty on lanes 250..255 (second T-half, exec-masked).
__global__ __launch_bounds__(256, 1) void viterbi_fwd(
    const float* __restrict__ feats, const float* __restrict__ mask,
    const float* __restrict__ trans, float* __restrict__ hist)
{
    const int b = blockIdx.x;
    const int tid = threadIdx.x;
    const int j = tid >> 1;            // 0..127
    const int h = tid & 1;             // i-half
    const bool evn = (h == 0);
    const bool dual = (tid >= 250);
    const int du = tid - 250;          // 0..5 (valid only if dual)
    const int j2 = 128 + ((du >> 1) & 3);  // 128..130
    const int h2 = du & 1;
    const bool dualE = dual && evn;    // tid 250,252,254

    __shared__ float sbuf[2][132];

    float4 T0[17];
    load_T_half(T0, trans, j, h);
    float4 Tx[17];
    if (dual) load_T_half(Tx, trans, j2, h2);

    // init both buffers: NEGV everywhere, [0][START]=0; slot 131 stays NEGV forever
    for (int q = tid; q < 2 * 132; q += 256) {
        int bufi = q / 132, idx = q - bufi * 132;
        sbuf[bufi][idx] = (bufi == 0 && idx == START_I) ? 0.f : NEGV;
    }
    __syncthreads();

    const float* fb = feats + (size_t)b * LL * CP;
    const float* mb = mask + (size_t)b * LL;
    float* hb = hist + (size_t)b * LL * CP;

    float s_reg = NEGV;                                   // j<128: never START
    float sx_reg = (j2 == START_I) ? 0.f : NEGV;          // dual evens only

    float fv0 = 0.f, fv1 = 0.f, fx0 = 0.f, fx1 = 0.f;
    float mv0 = mb[0], mv1 = mb[1];
    if (evn)  { fv0 = fb[j];  fv1 = fb[CP + j]; }
    if (dualE){ fx0 = fb[j2]; fx1 = fb[CP + j2]; }

    int cur = 0;
    float ns_p = 0.f, nsx_p = 0.f;

    for (int t = 0; t < LL; ++t) {
        // deferred hist stores from step t-1 (global, never drained by lds_barrier)
        if (t > 0) {
            if (evn)   hb[(size_t)(t - 1) * CP + j]  = ns_p;
            if (dualE) hb[(size_t)(t - 1) * CP + j2] = nsx_p;
        }
        // prefetch t+2 (latency hidden across 2 steps)
        float fv2 = 0.f, mv2 = 1.f, fx2 = 0.f;
        if (t + 2 < LL) {
            mv2 = mb[t + 2];
            if (evn)   fv2 = fb[(size_t)(t + 2) * CP + j];
            if (dualE) fx2 = fb[(size_t)(t + 2) * CP + j2];
        }

        // partial max over my i-half (broadcast b128 reads, 2 addrs/instr = free)
        const float4* s4 = (const float4*)&sbuf[cur][h * 64];
        float mx0 = -3.0e38f, mx1 = -3.0e38f;
#pragma unroll
        for (int q = 0; q < 17; ++q) {
            float4 sv = s4[q];
            mx0 = fmaxf(mx0, fmaxf(sv.x + T0[q].x, sv.y + T0[q].y));
            mx1 = fmaxf(mx1, fmaxf(sv.z + T0[q].z, sv.w + T0[q].w));
        }
        float p = fmaxf(mx0, mx1);
        float best = fmaxf(p, __shfl_xor(p, 1, 64));      // combine halves: ONE shfl

        float bx = 0.f;
        if (dual) {
            const float4* s4x = (const float4*)&sbuf[cur][h2 * 64];
            float ax0 = -3.0e38f, ax1 = -3.0e38f;
#pragma unroll
            for (int q = 0; q < 17; ++q) {
                float4 sv = s4x[q];
                ax0 = fmaxf(ax0, fmaxf(sv.x + Tx[q].x, sv.y + Tx[q].y));
                ax1 = fmaxf(ax1, fmaxf(sv.z + Tx[q].z, sv.w + Tx[q].w));
            }
            float p2 = fmaxf(ax0, ax1);
            bx = fmaxf(p2, __shfl_xor(p2, 1, 64));        // lanes 250..255 all active
        }

        // blend + publish (even lanes own columns)
        if (evn) {
            float ns = (mv0 != 0.f) ? (best + fv0) : s_reg;
            s_reg = ns;
            sbuf[cur ^ 1][j] = ns;
            ns_p = ns;
            if (dual) {
                float nsx = (mv0 != 0.f) ? (bx + fx0) : sx_reg;
                sx_reg = nsx;
                sbuf[cur ^ 1][j2] = nsx;
                nsx_p = nsx;
            }
        }
        lds_barrier();   // single barrier: publishes sbuf[cur^1], orders reads of sbuf[cur]

        fv0 = fv1; fv1 = fv2; mv0 = mv1; mv1 = mv2; fx0 = fx1; fx1 = fx2;
        cur ^= 1;
    }
    if (evn)   hb[(size_t)(LL - 1) * CP + j]  = ns_p;
    if (dualE) hb[(size_t)(LL - 1) * CP + j2] = nsx_p;
}

// ---------------- Kernel 3: backpointer matrix (unchanged) ----------------
__global__ __launch_bounds__(256, 4) void bp_kernel(
    const float* __restrict__ hist, const float* __restrict__ trans,
    unsigned char* __restrict__ bp)
{
    const int b  = blockIdx.x / 5;
    const int jc = blockIdx.x % 5;
    const int tc = blockIdx.y;
    const int tid = threadIdx.x;
    const int j0 = jc * 32;

    __shared__ float Ts[32][136];
    __shared__ float hs[8][132];

    for (int q = 0; q < 17; ++q) {
        int lin = tid + q * 256;
        if (lin < 32 * CC) {
            int r = lin / CC, i = lin - r * CC;
            if (j0 + r < CC) Ts[r][i] = trans[(size_t)(j0 + r) * CC + i];
        }
    }
    {
        const float4* src = (const float4*)(hist + ((size_t)b * LL + tc * 8) * CP);
#pragma unroll
        for (int q = 0; q < 2; ++q) {
            int lin = tid + q * 256;
            if (lin < (8 * CP) / 4) ((float4*)hs)[lin] = src[lin];
        }
    }
    __syncthreads();

    const int jl = tid & 31;
    const int tt = tid >> 5;
    const int j = j0 + jl;
    const int t = tc * 8 + tt + 1;
    if (j >= CC || t >= LL) return;

    float best; int idx;
    {
        float4 tv = *(const float4*)&Ts[jl][128];
        float4 hv = *(const float4*)&hs[tt][128];
        best = hv.z + tv.z; idx = 130;
        float v;
        v = hv.y + tv.y; if (v >= best) { best = v; idx = 129; }
        v = hv.x + tv.x; if (v >= best) { best = v; idx = 128; }
    }
#pragma unroll
    for (int i4 = 31; i4 >= 0; --i4) {
        float4 tv = *(const float4*)&Ts[jl][i4 * 4];
        float4 hv = *(const float4*)&hs[tt][i4 * 4];
        float v;
        v = hv.w + tv.w; if (v >= best) { best = v; idx = i4 * 4 + 3; }
        v = hv.z + tv.z; if (v >= best) { best = v; idx = i4 * 4 + 2; }
        v = hv.y + tv.y; if (v >= best) { best = v; idx = i4 * 4 + 1; }
        v = hv.x + tv.x; if (v >= best) { best = v; idx = i4 * 4 + 0; }
    }
    bp[((size_t)b * LL + t) * CP + j] = (unsigned char)idx;
}

// ---------------- Kernel 4: final argmax + LDS-streamed u8 backtrack (unchanged) ----------------
__global__ __launch_bounds__(64, 1) void viterbi_btr(
    const float* __restrict__ hist, const float* __restrict__ trans,
    const unsigned char* __restrict__ bp,
    float* __restrict__ out_score, float* __restrict__ out_path)
{
    const int b = blockIdx.x;
    const int lane = threadIdx.x;
    const float* hb = hist + ((size_t)b * LL + (LL - 1)) * CP;
    const float* ts = trans + (size_t)STOP_I * CC;

    float v0 = hb[lane] + ts[lane];
    float v1 = hb[lane + 64] + ts[lane + 64];
    float v2 = (lane < 3) ? (hb[lane + 128] + ts[lane + 128]) : -3.0e38f;

    float best = v0; int idx = lane;
    if (v1 > best) { best = v1; idx = lane + 64; }
    if (v2 > best) { best = v2; idx = lane + 128; }
#pragma unroll
    for (int off = 32; off >= 1; off >>= 1) {
        float ob = __shfl_xor(best, off, 64);
        int   oi = __shfl_xor(idx, off, 64);
        if (ob > best || (ob == best && oi < idx)) { best = ob; idx = oi; }
    }

    float* op = out_path + (size_t)b * LL;
    if (lane == 0) {
        out_score[b] = best;
        op[LL - 1] = (float)idx;
    }
    int tag = idx;

    __shared__ unsigned char buf[2][1088];
    const unsigned char* bpb = bp + (size_t)b * LL * CP;

    {
        const unsigned int* src = (const unsigned int*)(bpb + (size_t)504 * CP);
        unsigned int* dst = (unsigned int*)buf[1];
#pragma unroll
        for (int q = 0; q < 5; ++q) {
            int lin = lane + q * 64;
            if (lin < 264) dst[lin] = src[lin];
        }
    }
    lds_barrier();

    int cur = 1;
    for (int k = 63; k >= 0; --k) {
        unsigned int r0 = 0, r1 = 0, r2 = 0, r3 = 0, r4 = 0;
        if (k > 0) {
            const unsigned int* src = (const unsigned int*)(bpb + (size_t)(k - 1) * 8 * CP);
            r0 = src[lane];
            r1 = src[lane + 64];
            r2 = src[lane + 128];
            r3 = src[lane + 192];
            if (lane < 8) r4 = src[lane + 256];
        }
        const unsigned char* cb = buf[cur];
#pragma unroll
        for (int s = 7; s >= 0; --s) {
            int t = k * 8 + s;
            if (t >= 1) {
                tag = cb[s * CP + tag];
                if (lane == 0) op[t - 1] = (float)tag;
            }
        }
        if (k > 0) {
            unsigned int* dst = (unsigned int*)buf[cur ^ 1];
            dst[lane] = r0;
            dst[lane + 64] = r1;
            dst[lane + 128] = r2;
            dst[lane + 192] = r3;
            if (lane < 8) dst[lane + 256] = r4;
            lds_barrier();
        }
        cur ^= 1;
    }
}

extern "C" void kernel_launch(void* const* d_in, const int* in_sizes, int n_in,
                              void* d_out, int out_size, void* d_ws, size_t ws_size,
                              hipStream_t stream)
{
    const float* x     = (const float*)d_in[0];
    const float* mask  = (const float*)d_in[1];
    const float* W     = (const float*)d_in[2];
    const float* bias  = (const float*)d_in[3];
    const float* trans = (const float*)d_in[4];

    float* feats = (float*)d_ws;
    float* hist  = feats + (size_t)BB * LL * CP;
    unsigned char* bp = (unsigned char*)(hist + (size_t)BB * LL * CP);
    float* out_score = (float*)d_out;
    float* out_path  = out_score + BB;

    hipLaunchKernelGGL(gemm_feats, dim3((BB * LL) / GM), dim3(256), 0, stream, x, W, bias, feats);
    hipLaunchKernelGGL(viterbi_fwd, dim3(BB), dim3(256), 0, stream, feats, mask, trans, hist);
    hipLaunchKernelGGL(bp_kernel, dim3(BB * 5, 64), dim3(256), 0, stream, hist, trans, bp);
    hipLaunchKernelGGL(viterbi_btr, dim3(BB), dim3(64), 0, stream, hist, trans, bp, out_score, out_path);
}

// Round 6
// 841.995 us; speedup vs baseline: 1.1053x; 1.0527x over previous
//
#include <hip/hip_runtime.h>

#define BB 64
#define LL 512
#define DD 1024
#define CC 131
#define CP 132
#define START_I 129
#define STOP_I 130
#define NEGV -10000.0f

// Raw workgroup barrier: makes LDS writes visible without draining vmcnt
// (so global stores/prefetches stay in flight across steps).
__device__ __forceinline__ void lds_barrier() {
    asm volatile("s_waitcnt lgkmcnt(0)" ::: "memory");
    __builtin_amdgcn_s_barrier();
    __builtin_amdgcn_sched_barrier(0);
}

// ---------------- Kernel 1: feats[m][c] = dot(x[m,:], W[c,:]) + b[c] ----------------
#define GM 128
#define GK 32
#define LSTR 36

__global__ __launch_bounds__(256, 1) void gemm_feats(
    const float* __restrict__ x, const float* __restrict__ W,
    const float* __restrict__ bias, float* __restrict__ feats)
{
    __shared__ float xs[GM * LSTR];   // [m][k]
    __shared__ float ws[CP * LSTR];   // [j][k]

    const int tid = threadIdx.x;
    const int m0 = blockIdx.x * GM;
    const int tm = tid & 15;          // rows tm + 16r
    const int tj = (tid >> 4) & 15;   // cols tj + 16c
    const bool tail = (tj < 3);
    const int tjt = (tj < 3) ? tj : 2;

    float acc[8][8];
    float acct[8];
#pragma unroll
    for (int r = 0; r < 8; ++r) {
        acct[r] = 0.f;
#pragma unroll
        for (int c = 0; c < 8; ++c) acc[r][c] = 0.f;
    }

    for (int kc = 0; kc < DD / GK; ++kc) {
        const int k0 = kc * GK;
        if (kc) __syncthreads();
#pragma unroll
        for (int q = 0; q < 4; ++q) {
            int lin = tid + q * 256;
            int m = lin >> 3, c4 = lin & 7;
            float4 v = *(const float4*)&x[(size_t)(m0 + m) * DD + k0 + c4 * 4];
            *(float4*)&xs[m * LSTR + c4 * 4] = v;
        }
#pragma unroll
        for (int q = 0; q < 5; ++q) {
            int lin = tid + q * 256;
            if (lin < CC * 8) {
                int r = lin >> 3, c4 = lin & 7;
                float4 v = *(const float4*)&W[(size_t)r * DD + k0 + c4 * 4];
                *(float4*)&ws[r * LSTR + c4 * 4] = v;
            }
        }
        __syncthreads();

#pragma unroll
        for (int k4 = 0; k4 < 8; ++k4) {
            float4 xr[8], wr[8], wt;
#pragma unroll
            for (int r = 0; r < 8; ++r)
                xr[r] = *(const float4*)&xs[(tm + 16 * r) * LSTR + k4 * 4];
#pragma unroll
            for (int c = 0; c < 8; ++c)
                wr[c] = *(const float4*)&ws[(tj + 16 * c) * LSTR + k4 * 4];
            wt = *(const float4*)&ws[(128 + tjt) * LSTR + k4 * 4];
#pragma unroll
            for (int r = 0; r < 8; ++r) {
#pragma unroll
                for (int c = 0; c < 8; ++c) {
                    acc[r][c] = fmaf(xr[r].x, wr[c].x, acc[r][c]);
                    acc[r][c] = fmaf(xr[r].y, wr[c].y, acc[r][c]);
                    acc[r][c] = fmaf(xr[r].z, wr[c].z, acc[r][c]);
                    acc[r][c] = fmaf(xr[r].w, wr[c].w, acc[r][c]);
                }
                acct[r] = fmaf(xr[r].x, wt.x, acct[r]);
                acct[r] = fmaf(xr[r].y, wt.y, acct[r]);
                acct[r] = fmaf(xr[r].z, wt.z, acct[r]);
                acct[r] = fmaf(xr[r].w, wt.w, acct[r]);
            }
        }
    }

#pragma unroll
    for (int c = 0; c < 8; ++c) {
        int j = tj + 16 * c;
        float bv = bias[j];
#pragma unroll
        for (int r = 0; r < 8; ++r)
            feats[(size_t)(m0 + tm + 16 * r) * CP + j] = acc[r][c] + bv;
    }
    if (tail) {
        int j = 128 + tj;
        float bv = bias[j];
#pragma unroll
        for (int r = 0; r < 8; ++r)
            feats[(size_t)(m0 + tm + 16 * r) * CP + j] = acct[r] + bv;
    }
}

// ---------------- Kernel 2: Viterbi forward, full-col-per-lane, broadcast scan --------
// 64 blocks x 192 threads (3 waves). Wave 0: cols 0..63, wave 1: cols 64..127 — each
// lane holds the FULL 131-float T row (33 float4) and scans sbuf at wave-uniform
// addresses (pure LDS broadcast, zero bank conflicts, zero shuffles). Wave 2 lanes 0..5
// handle cols 128..130 pair-split (half-row each, one shfl). One lgkm barrier / step.
__global__ __attribute__((amdgpu_flat_work_group_size(192, 192), amdgpu_waves_per_eu(1, 1)))
void viterbi_fwd(
    const float* __restrict__ feats, const float* __restrict__ mask,
    const float* __restrict__ trans, float* __restrict__ hist)
{
    const int b = blockIdx.x;
    const int tid = threadIdx.x;
    const int wave = tid >> 6, lane = tid & 63;
    const bool fullw = (wave < 2);
    const int du = (lane < 6) ? lane : 5;           // dual-unit clamp for wave 2
    const int colc = fullw ? (wave * 64 + lane)     // 0..127
                           : (128 + (du >> 1));     // 128..130 (clamped for lanes>=6)
    const int h = lane & 1;                          // wave-2 i-half
    const bool owner = fullw || (lane < 6 && h == 0);

    __shared__ float sbuf[2][132];

    // ---- T row(s): full row for waves 0/1; half row (17 f4) for wave 2 ----
    float4 T[33];
    if (fullw) {
        const float* tr = trans + (size_t)colc * CC;
#pragma unroll
        for (int q = 0; q < 32; ++q) {
            T[q].x = tr[4 * q + 0]; T[q].y = tr[4 * q + 1];
            T[q].z = tr[4 * q + 2]; T[q].w = tr[4 * q + 3];
        }
        T[32].x = tr[128]; T[32].y = tr[129]; T[32].z = tr[130];
        T[32].w = NEGV;                                // pad i=131
    } else {
        const float* tr = trans + (size_t)colc * CC + h * 64;
        if (h == 0) {
#pragma unroll
            for (int q = 0; q < 16; ++q) {
                T[q].x = tr[4 * q + 0]; T[q].y = tr[4 * q + 1];
                T[q].z = tr[4 * q + 2]; T[q].w = tr[4 * q + 3];
            }
            T[16] = make_float4(NEGV, NEGV, NEGV, NEGV);   // pairs s[64..67]
        } else {
#pragma unroll
            for (int q = 0; q < 16; ++q) {
                T[q].x = tr[4 * q + 0]; T[q].y = tr[4 * q + 1];
                T[q].z = tr[4 * q + 2]; T[q].w = tr[4 * q + 3];
            }
            T[16].x = tr[64]; T[16].y = tr[65]; T[16].z = tr[66];  // i=128..130
            T[16].w = NEGV;
        }
#pragma unroll
        for (int q = 17; q < 33; ++q) T[q] = make_float4(NEGV, NEGV, NEGV, NEGV);
    }
    // keep-alive: force T into VGPRs, block remat/sinking into the loop
#pragma unroll
    for (int q = 0; q < 33; ++q)
        asm volatile("" : "+v"(T[q].x), "+v"(T[q].y), "+v"(T[q].z), "+v"(T[q].w));

    // init both buffers: NEGV everywhere, [0][START]=0; slot 131 stays NEGV forever
    for (int q = tid; q < 2 * 132; q += 192) {
        int bufi = q / 132, idx = q - bufi * 132;
        sbuf[bufi][idx] = (bufi == 0 && idx == START_I) ? 0.f : NEGV;
    }
    __syncthreads();

    const float* fb = feats + (size_t)b * LL * CP;
    const float* mb = mask + (size_t)b * LL;
    float* hb = hist + (size_t)b * LL * CP;

    float s_reg = (colc == START_I) ? 0.f : NEGV;

    // rotating prefetch (depth 2); running pointers (no per-step 64-bit mul)
    float fv0 = fb[colc], fv1 = fb[CP + colc];
    float mv0 = mb[0], mv1 = mb[1];
    const float* fb_t = fb + 2 * CP + colc;
    const float* mb_t = mb + 2;
    float* hb_t = hb + colc;

    int cur = 0;
    float ns_p = 0.f;

    for (int t = 0; t < LL; ++t) {
        // deferred hist store from step t-1 (global; never drained by lds_barrier)
        if (t > 0) {
            if (owner) *hb_t = ns_p;
            hb_t += CP;
        }
        // prefetch t+2
        float fv2 = 0.f, mv2 = 1.f;
        if (t + 2 < LL) { fv2 = *fb_t; mv2 = *mb_t; }
        fb_t += CP; ++mb_t;

        float best;
        if (fullw) {
            // broadcast scan: all 64 lanes read the SAME address -> no conflicts
            const float4* s4 = (const float4*)sbuf[cur];
            float m0 = -3.0e38f, m1 = -3.0e38f, m2 = -3.0e38f, m3 = -3.0e38f;
#pragma unroll
            for (int q = 0; q < 32; q += 2) {
                float4 a = s4[q];
                m0 = fmaxf(fmaxf(a.x + T[q].x, a.y + T[q].y), m0);       // v_max3
                m1 = fmaxf(fmaxf(a.z + T[q].z, a.w + T[q].w), m1);
                float4 c = s4[q + 1];
                m2 = fmaxf(fmaxf(c.x + T[q + 1].x, c.y + T[q + 1].y), m2);
                m3 = fmaxf(fmaxf(c.z + T[q + 1].z, c.w + T[q + 1].w), m3);
            }
            {
                float4 a = s4[32];
                m0 = fmaxf(fmaxf(a.x + T[32].x, a.y + T[32].y), m0);
                m1 = fmaxf(fmaxf(a.z + T[32].z, a.w + T[32].w), m1);
            }
            best = fmaxf(fmaxf(m0, m1), fmaxf(m2, m3));
        } else {
            // pair-split half scan for cols 128..130 (2 addrs/read: tiny 2-way, 17 reads)
            const float4* s4 = (const float4*)&sbuf[cur][h * 64];
            float m0 = -3.0e38f, m1 = -3.0e38f;
#pragma unroll
            for (int q = 0; q < 17; ++q) {
                float4 a = s4[q];
                m0 = fmaxf(fmaxf(a.x + T[q].x, a.y + T[q].y), m0);
                m1 = fmaxf(fmaxf(a.z + T[q].z, a.w + T[q].w), m1);
            }
            float p = fmaxf(m0, m1);
            best = fmaxf(p, __shfl_xor(p, 1, 64));
        }

        float ns = (mv0 != 0.f) ? (best + fv0) : s_reg;
        s_reg = ns;
        if (owner) sbuf[cur ^ 1][colc] = ns;
        ns_p = ns;

        lds_barrier();   // publish sbuf[cur^1]; lgkm-only (global ops stay in flight)

        fv0 = fv1; fv1 = fv2; mv0 = mv1; mv1 = mv2;
        cur ^= 1;
    }
    if (owner) *hb_t = ns_p;   // row LL-1
}

// ---------------- Kernel 3: backpointer matrix (unchanged) ----------------
__global__ __launch_bounds__(256, 4) void bp_kernel(
    const float* __restrict__ hist, const float* __restrict__ trans,
    unsigned char* __restrict__ bp)
{
    const int b  = blockIdx.x / 5;
    const int jc = blockIdx.x % 5;
    const int tc = blockIdx.y;
    const int tid = threadIdx.x;
    const int j0 = jc * 32;

    __shared__ float Ts[32][136];
    __shared__ float hs[8][132];

    for (int q = 0; q < 17; ++q) {
        int lin = tid + q * 256;
        if (lin < 32 * CC) {
            int r = lin / CC, i = lin - r * CC;
            if (j0 + r < CC) Ts[r][i] = trans[(size_t)(j0 + r) * CC + i];
        }
    }
    {
        const float4* src = (const float4*)(hist + ((size_t)b * LL + tc * 8) * CP);
#pragma unroll
        for (int q = 0; q < 2; ++q) {
            int lin = tid + q * 256;
            if (lin < (8 * CP) / 4) ((float4*)hs)[lin] = src[lin];
        }
    }
    __syncthreads();

    const int jl = tid & 31;
    const int tt = tid >> 5;
    const int j = j0 + jl;
    const int t = tc * 8 + tt + 1;
    if (j >= CC || t >= LL) return;

    float best; int idx;
    {
        float4 tv = *(const float4*)&Ts[jl][128];
        float4 hv = *(const float4*)&hs[tt][128];
        best = hv.z + tv.z; idx = 130;
        float v;
        v = hv.y + tv.y; if (v >= best) { best = v; idx = 129; }
        v = hv.x + tv.x; if (v >= best) { best = v; idx = 128; }
    }
#pragma unroll
    for (int i4 = 31; i4 >= 0; --i4) {
        float4 tv = *(const float4*)&Ts[jl][i4 * 4];
        float4 hv = *(const float4*)&hs[tt][i4 * 4];
        float v;
        v = hv.w + tv.w; if (v >= best) { best = v; idx = i4 * 4 + 3; }
        v = hv.z + tv.z; if (v >= best) { best = v; idx = i4 * 4 + 2; }
        v = hv.y + tv.y; if (v >= best) { best = v; idx = i4 * 4 + 1; }
        v = hv.x + tv.x; if (v >= best) { best = v; idx = i4 * 4 + 0; }
    }
    bp[((size_t)b * LL + t) * CP + j] = (unsigned char)idx;
}

// ---------------- Kernel 4: final argmax + LDS-streamed u8 backtrack (unchanged) ----------------
__global__ __launch_bounds__(64, 1) void viterbi_btr(
    const float* __restrict__ hist, const float* __restrict__ trans,
    const unsigned char* __restrict__ bp,
    float* __restrict__ out_score, float* __restrict__ out_path)
{
    const int b = blockIdx.x;
    const int lane = threadIdx.x;
    const float* hb = hist + ((size_t)b * LL + (LL - 1)) * CP;
    const float* ts = trans + (size_t)STOP_I * CC;

    float v0 = hb[lane] + ts[lane];
    float v1 = hb[lane + 64] + ts[lane + 64];
    float v2 = (lane < 3) ? (hb[lane + 128] + ts[lane + 128]) : -3.0e38f;

    float best = v0; int idx = lane;
    if (v1 > best) { best = v1; idx = lane + 64; }
    if (v2 > best) { best = v2; idx = lane + 128; }
#pragma unroll
    for (int off = 32; off >= 1; off >>= 1) {
        float ob = __shfl_xor(best, off, 64);
        int   oi = __shfl_xor(idx, off, 64);
        if (ob > best || (ob == best && oi < idx)) { best = ob; idx = oi; }
    }

    float* op = out_path + (size_t)b * LL;
    if (lane == 0) {
        out_score[b] = best;
        op[LL - 1] = (float)idx;
    }
    int tag = idx;

    __shared__ unsigned char buf[2][1088];
    const unsigned char* bpb = bp + (size_t)b * LL * CP;

    {
        const unsigned int* src = (const unsigned int*)(bpb + (size_t)504 * CP);
        unsigned int* dst = (unsigned int*)buf[1];
#pragma unroll
        for (int q = 0; q < 5; ++q) {
            int lin = lane + q * 64;
            if (lin < 264) dst[lin] = src[lin];
        }
    }
    lds_barrier();

    int cur = 1;
    for (int k = 63; k >= 0; --k) {
        unsigned int r0 = 0, r1 = 0, r2 = 0, r3 = 0, r4 = 0;
        if (k > 0) {
            const unsigned int* src = (const unsigned int*)(bpb + (size_t)(k - 1) * 8 * CP);
            r0 = src[lane];
            r1 = src[lane + 64];
            r2 = src[lane + 128];
            r3 = src[lane + 192];
            if (lane < 8) r4 = src[lane + 256];
        }
        const unsigned char* cb = buf[cur];
#pragma unroll
        for (int s = 7; s >= 0; --s) {
            int t = k * 8 + s;
            if (t >= 1) {
                tag = cb[s * CP + tag];
                if (lane == 0) op[t - 1] = (float)tag;
            }
        }
        if (k > 0) {
            unsigned int* dst = (unsigned int*)buf[cur ^ 1];
            dst[lane] = r0;
            dst[lane + 64] = r1;
            dst[lane + 128] = r2;
            dst[lane + 192] = r3;
            if (lane < 8) dst[lane + 256] = r4;
            lds_barrier();
        }
        cur ^= 1;
    }
}

extern "C" void kernel_launch(void* const* d_in, const int* in_sizes, int n_in,
                              void* d_out, int out_size, void* d_ws, size_t ws_size,
                              hipStream_t stream)
{
    const float* x     = (const float*)d_in[0];
    const float* mask  = (const float*)d_in[1];
    const float* W     = (const float*)d_in[2];
    const float* bias  = (const float*)d_in[3];
    const float* trans = (const float*)d_in[4];

    float* feats = (float*)d_ws;
    float* hist  = feats + (size_t)BB * LL * CP;
    unsigned char* bp = (unsigned char*)(hist + (size_t)BB * LL * CP);
    float* out_score = (float*)d_out;
    float* out_path  = out_score + BB;

    hipLaunchKernelGGL(gemm_feats, dim3((BB * LL) / GM), dim3(256), 0, stream, x, W, bias, feats);
    hipLaunchKernelGGL(viterbi_fwd, dim3(BB), dim3(192), 0, stream, feats, mask, trans, hist);
    hipLaunchKernelGGL(bp_kernel, dim3(BB * 5, 64), dim3(256), 0, stream, hist, trans, bp);
    hipLaunchKernelGGL(viterbi_btr, dim3(BB), dim3(64), 0, stream, hist, trans, bp, out_score, out_path);
}

// Round 7
// 732.583 us; speedup vs baseline: 1.2704x; 1.1494x over previous
//
#include <hip/hip_runtime.h>

#define BB 64
#define LL 512
#define DD 1024
#define CC 131
#define CP 132
#define START_I 129
#define STOP_I 130
#define NEGV -10000.0f

// Raw workgroup barrier: makes LDS writes visible without draining vmcnt
// (so global stores/prefetches stay in flight across steps).
__device__ __forceinline__ void lds_barrier() {
    asm volatile("s_waitcnt lgkmcnt(0)" ::: "memory");
    __builtin_amdgcn_s_barrier();
    __builtin_amdgcn_sched_barrier(0);
}

// lane-broadcast read: value of lane `i` of this wave's register, lands in SGPR
#define RL(src, i) __int_as_float(__builtin_amdgcn_readlane(__float_as_int(src), (i)))

// ---------------- Kernel 1: feats[m][c] = dot(x[m,:], W[c,:]) + b[c] ----------------
// GM=64 -> 512 blocks = 2 blocks/CU: block A's staging overlaps block B's FMAs.
#define GM 64
#define GK 32
#define LSTR 36

__global__ __launch_bounds__(256, 2) void gemm_feats(
    const float* __restrict__ x, const float* __restrict__ W,
    const float* __restrict__ bias, float* __restrict__ feats)
{
    __shared__ float xs[GM * LSTR];   // [m][k] 64x36
    __shared__ float ws[CP * LSTR];   // [j][k] 132x36

    const int tid = threadIdx.x;
    const int m0 = blockIdx.x * GM;
    const int tm = tid & 15;          // rows tm + 16r (r<4)
    const int tj = (tid >> 4) & 15;   // cols tj + 16c (c<8)
    const bool tail = (tj < 3);
    const int tjt = (tj < 3) ? tj : 2;

    float acc[4][8];
    float acct[4];
#pragma unroll
    for (int r = 0; r < 4; ++r) {
        acct[r] = 0.f;
#pragma unroll
        for (int c = 0; c < 8; ++c) acc[r][c] = 0.f;
    }

    for (int kc = 0; kc < DD / GK; ++kc) {
        const int k0 = kc * GK;
        if (kc) __syncthreads();
        // stage x: 64 rows x 32 k = 512 float4
#pragma unroll
        for (int q = 0; q < 2; ++q) {
            int lin = tid + q * 256;
            int m = lin >> 3, c4 = lin & 7;
            float4 v = *(const float4*)&x[(size_t)(m0 + m) * DD + k0 + c4 * 4];
            *(float4*)&xs[m * LSTR + c4 * 4] = v;
        }
        // stage W: 131 rows x 32 k = 1048 float4
#pragma unroll
        for (int q = 0; q < 5; ++q) {
            int lin = tid + q * 256;
            if (lin < CC * 8) {
                int r = lin >> 3, c4 = lin & 7;
                float4 v = *(const float4*)&W[(size_t)r * DD + k0 + c4 * 4];
                *(float4*)&ws[r * LSTR + c4 * 4] = v;
            }
        }
        __syncthreads();

#pragma unroll
        for (int k4 = 0; k4 < 8; ++k4) {
            float4 xr[4], wr[8], wt;
#pragma unroll
            for (int r = 0; r < 4; ++r)
                xr[r] = *(const float4*)&xs[(tm + 16 * r) * LSTR + k4 * 4];
#pragma unroll
            for (int c = 0; c < 8; ++c)
                wr[c] = *(const float4*)&ws[(tj + 16 * c) * LSTR + k4 * 4];
            wt = *(const float4*)&ws[(128 + tjt) * LSTR + k4 * 4];
#pragma unroll
            for (int r = 0; r < 4; ++r) {
#pragma unroll
                for (int c = 0; c < 8; ++c) {
                    acc[r][c] = fmaf(xr[r].x, wr[c].x, acc[r][c]);
                    acc[r][c] = fmaf(xr[r].y, wr[c].y, acc[r][c]);
                    acc[r][c] = fmaf(xr[r].z, wr[c].z, acc[r][c]);
                    acc[r][c] = fmaf(xr[r].w, wr[c].w, acc[r][c]);
                }
                acct[r] = fmaf(xr[r].x, wt.x, acct[r]);
                acct[r] = fmaf(xr[r].y, wt.y, acct[r]);
                acct[r] = fmaf(xr[r].z, wt.z, acct[r]);
                acct[r] = fmaf(xr[r].w, wt.w, acct[r]);
            }
        }
    }

#pragma unroll
    for (int c = 0; c < 8; ++c) {
        int j = tj + 16 * c;
        float bv = bias[j];
#pragma unroll
        for (int r = 0; r < 4; ++r)
            feats[(size_t)(m0 + tm + 16 * r) * CP + j] = acc[r][c] + bv;
    }
    if (tail) {
        int j = 128 + tj;
        float bv = bias[j];
#pragma unroll
        for (int r = 0; r < 4; ++r)
            feats[(size_t)(m0 + tm + 16 * r) * CP + j] = acct[r] + bv;
    }
}

// ---------------- Kernel 2: Viterbi forward, readlane fan-out (LDS out of the loop) ---
// 64 blocks x 192 threads (3 waves on 3 SIMDs). Wave 0: cols 0..63, wave 1: 64..127,
// wave 2: cols 128..130 on lanes 0..2 (rest clamped, non-owner). Per step each wave:
// 5 tiny ds_reads (sa=s[lane], sb=s[64+lane], 3 uniform tails), then 128 v_readlane
// SGPR broadcasts fused into add/max3 trees -- VALU pipe only, per-SIMD parallel.
// One lgkm barrier/step. fmax trees are exact => hist bit-identical to reference order.
__global__ __launch_bounds__(192, 1) void viterbi_fwd(
    const float* __restrict__ feats, const float* __restrict__ mask,
    const float* __restrict__ trans, float* __restrict__ hist)
{
    const int b = blockIdx.x;
    const int tid = threadIdx.x;
    const int wave = tid >> 6, lane = tid & 63;
    const int colc = (wave < 2) ? (wave * 64 + lane)
                                : (128 + ((lane < 2) ? lane : 2));
    const bool owner = (wave < 2) || (lane < 3);

    __shared__ float sbuf[2][132];

    // ---- full T row in VGPRs: 33 float4 = 132 floats ----
    float4 T[33];
    {
        const float* tr = trans + (size_t)colc * CC;
#pragma unroll
        for (int q = 0; q < 32; ++q) {
            T[q].x = tr[4 * q + 0]; T[q].y = tr[4 * q + 1];
            T[q].z = tr[4 * q + 2]; T[q].w = tr[4 * q + 3];
        }
        T[32].x = tr[128]; T[32].y = tr[129]; T[32].z = tr[130];
        T[32].w = NEGV;
    }
    // tie loads to opaque results: later uses MUST come from these registers (or
    // scratch spill) -- re-loading from trans is no longer legal for the compiler.
#pragma unroll
    for (int q = 0; q < 33; ++q)
        asm volatile("" : "+v"(T[q].x), "+v"(T[q].y), "+v"(T[q].z), "+v"(T[q].w));

    // init sbuf[0] (NEGV, START=0); sbuf[1] fully written each step before read
    for (int q = tid; q < 2 * 132; q += 192) {
        int bufi = q / 132, idx = q - bufi * 132;
        sbuf[bufi][idx] = (bufi == 0 && idx == START_I) ? 0.f : NEGV;
    }
    __syncthreads();

    const float* fb = feats + (size_t)b * LL * CP;
    const float* mb = mask + (size_t)b * LL;
    float* hb = hist + (size_t)b * LL * CP;

    float s_reg = (colc == START_I) ? 0.f : NEGV;

    // depth-2 prefetch ring; running pointers
    float fv0 = fb[colc], fv1 = fb[CP + colc];
    float mv0 = mb[0], mv1 = mb[1];
    const float* fb_t = fb + 2 * CP + colc;
    const float* mb_t = mb + 2;
    float* hb_t = hb + colc;

    int cur = 0;
    float ns_p = 0.f;

    for (int t = 0; t < LL; ++t) {
        // deferred hist store from step t-1 (global; stays in flight across barrier)
        if (t > 0) {
            if (owner) *hb_t = ns_p;
            hb_t += CP;
        }
        // prefetch t+2
        float fv2 = 0.f, mv2 = 1.f;
        if (t + 2 < LL) { fv2 = *fb_t; mv2 = *mb_t; }
        fb_t += CP; ++mb_t;

        // fan-in: 2 lane-strided + 3 uniform reads (the ONLY LDS reads this step)
        float sa = sbuf[cur][lane];          // s[0..63] across lanes
        float sb = sbuf[cur][64 + lane];     // s[64..127] across lanes
        float s128 = sbuf[cur][128], s129 = sbuf[cur][129], s130 = sbuf[cur][130];

        // scan: readlane broadcast -> add -> max3, 4 independent chains
        float a0 = -3.0e38f, a1 = -3.0e38f, a2 = -3.0e38f, a3 = -3.0e38f;
#pragma unroll
        for (int q = 0; q < 16; ++q) {
            float4 t4 = T[q];
            a0 = fmaxf(fmaxf(RL(sa, 4 * q + 0) + t4.x, RL(sa, 4 * q + 1) + t4.y), a0);
            a1 = fmaxf(fmaxf(RL(sa, 4 * q + 2) + t4.z, RL(sa, 4 * q + 3) + t4.w), a1);
        }
#pragma unroll
        for (int q = 0; q < 16; ++q) {
            float4 t4 = T[16 + q];
            a2 = fmaxf(fmaxf(RL(sb, 4 * q + 0) + t4.x, RL(sb, 4 * q + 1) + t4.y), a2);
            a3 = fmaxf(fmaxf(RL(sb, 4 * q + 2) + t4.z, RL(sb, 4 * q + 3) + t4.w), a3);
        }
        {
            float4 t4 = T[32];
            a0 = fmaxf(fmaxf(s128 + t4.x, s129 + t4.y), a0);
            a1 = fmaxf(a1, s130 + t4.z);
        }
        float best = fmaxf(fmaxf(a0, a1), fmaxf(a2, a3));

        float ns = (mv0 != 0.f) ? (best + fv0) : s_reg;
        s_reg = ns;
        if (owner) sbuf[cur ^ 1][colc] = ns;
        ns_p = ns;

        lds_barrier();   // publish sbuf[cur^1]; orders reads of sbuf[cur]

        fv0 = fv1; fv1 = fv2; mv0 = mv1; mv1 = mv2;
        cur ^= 1;
    }
    if (owner) *hb_t = ns_p;   // row LL-1
}

// ---------------- Kernel 3: backpointer matrix (unchanged) ----------------
__global__ __launch_bounds__(256, 4) void bp_kernel(
    const float* __restrict__ hist, const float* __restrict__ trans,
    unsigned char* __restrict__ bp)
{
    const int b  = blockIdx.x / 5;
    const int jc = blockIdx.x % 5;
    const int tc = blockIdx.y;
    const int tid = threadIdx.x;
    const int j0 = jc * 32;

    __shared__ float Ts[32][136];
    __shared__ float hs[8][132];

    for (int q = 0; q < 17; ++q) {
        int lin = tid + q * 256;
        if (lin < 32 * CC) {
            int r = lin / CC, i = lin - r * CC;
            if (j0 + r < CC) Ts[r][i] = trans[(size_t)(j0 + r) * CC + i];
        }
    }
    {
        const float4* src = (const float4*)(hist + ((size_t)b * LL + tc * 8) * CP);
#pragma unroll
        for (int q = 0; q < 2; ++q) {
            int lin = tid + q * 256;
            if (lin < (8 * CP) / 4) ((float4*)hs)[lin] = src[lin];
        }
    }
    __syncthreads();

    const int jl = tid & 31;
    const int tt = tid >> 5;
    const int j = j0 + jl;
    const int t = tc * 8 + tt + 1;
    if (j >= CC || t >= LL) return;

    float best; int idx;
    {
        float4 tv = *(const float4*)&Ts[jl][128];
        float4 hv = *(const float4*)&hs[tt][128];
        best = hv.z + tv.z; idx = 130;
        float v;
        v = hv.y + tv.y; if (v >= best) { best = v; idx = 129; }
        v = hv.x + tv.x; if (v >= best) { best = v; idx = 128; }
    }
#pragma unroll
    for (int i4 = 31; i4 >= 0; --i4) {
        float4 tv = *(const float4*)&Ts[jl][i4 * 4];
        float4 hv = *(const float4*)&hs[tt][i4 * 4];
        float v;
        v = hv.w + tv.w; if (v >= best) { best = v; idx = i4 * 4 + 3; }
        v = hv.z + tv.z; if (v >= best) { best = v; idx = i4 * 4 + 2; }
        v = hv.y + tv.y; if (v >= best) { best = v; idx = i4 * 4 + 1; }
        v = hv.x + tv.x; if (v >= best) { best = v; idx = i4 * 4 + 0; }
    }
    bp[((size_t)b * LL + t) * CP + j] = (unsigned char)idx;
}

// ---------------- Kernel 4: final argmax + LDS-streamed u8 backtrack (unchanged) ------
__global__ __launch_bounds__(64, 1) void viterbi_btr(
    const float* __restrict__ hist, const float* __restrict__ trans,
    const unsigned char* __restrict__ bp,
    float* __restrict__ out_score, float* __restrict__ out_path)
{
    const int b = blockIdx.x;
    const int lane = threadIdx.x;
    const float* hb = hist + ((size_t)b * LL + (LL - 1)) * CP;
    const float* ts = trans + (size_t)STOP_I * CC;

    float v0 = hb[lane] + ts[lane];
    float v1 = hb[lane + 64] + ts[lane + 64];
    float v2 = (lane < 3) ? (hb[lane + 128] + ts[lane + 128]) : -3.0e38f;

    float best = v0; int idx = lane;
    if (v1 > best) { best = v1; idx = lane + 64; }
    if (v2 > best) { best = v2; idx = lane + 128; }
#pragma unroll
    for (int off = 32; off >= 1; off >>= 1) {
        float ob = __shfl_xor(best, off, 64);
        int   oi = __shfl_xor(idx, off, 64);
        if (ob > best || (ob == best && oi < idx)) { best = ob; idx = oi; }
    }

    float* op = out_path + (size_t)b * LL;
    if (lane == 0) {
        out_score[b] = best;
        op[LL - 1] = (float)idx;
    }
    int tag = idx;

    __shared__ unsigned char buf[2][1088];
    const unsigned char* bpb = bp + (size_t)b * LL * CP;

    {
        const unsigned int* src = (const unsigned int*)(bpb + (size_t)504 * CP);
        unsigned int* dst = (unsigned int*)buf[1];
#pragma unroll
        for (int q = 0; q < 5; ++q) {
            int lin = lane + q * 64;
            if (lin < 264) dst[lin] = src[lin];
        }
    }
    lds_barrier();

    int cur = 1;
    for (int k = 63; k >= 0; --k) {
        unsigned int r0 = 0, r1 = 0, r2 = 0, r3 = 0, r4 = 0;
        if (k > 0) {
            const unsigned int* src = (const unsigned int*)(bpb + (size_t)(k - 1) * 8 * CP);
            r0 = src[lane];
            r1 = src[lane + 64];
            r2 = src[lane + 128];
            r3 = src[lane + 192];
            if (lane < 8) r4 = src[lane + 256];
        }
        const unsigned char* cb = buf[cur];
#pragma unroll
        for (int s = 7; s >= 0; --s) {
            int t = k * 8 + s;
            if (t >= 1) {
                tag = cb[s * CP + tag];
                if (lane == 0) op[t - 1] = (float)tag;
            }
        }
        if (k > 0) {
            unsigned int* dst = (unsigned int*)buf[cur ^ 1];
            dst[lane] = r0;
            dst[lane + 64] = r1;
            dst[lane + 128] = r2;
            dst[lane + 192] = r3;
            if (lane < 8) dst[lane + 256] = r4;
            lds_barrier();
        }
        cur ^= 1;
    }
}

extern "C" void kernel_launch(void* const* d_in, const int* in_sizes, int n_in,
                              void* d_out, int out_size, void* d_ws, size_t ws_size,
                              hipStream_t stream)
{
    const float* x     = (const float*)d_in[0];
    const float* mask  = (const float*)d_in[1];
    const float* W     = (const float*)d_in[2];
    const float* bias  = (const float*)d_in[3];
    const float* trans = (const float*)d_in[4];

    float* feats = (float*)d_ws;
    float* hist  = feats + (size_t)BB * LL * CP;
    unsigned char* bp = (unsigned char*)(hist + (size_t)BB * LL * CP);
    float* out_score = (float*)d_out;
    float* out_path  = out_score + BB;

    hipLaunchKernelGGL(gemm_feats, dim3((BB * LL) / GM), dim3(256), 0, stream, x, W, bias, feats);
    hipLaunchKernelGGL(viterbi_fwd, dim3(BB), dim3(192), 0, stream, feats, mask, trans, hist);
    hipLaunchKernelGGL(bp_kernel, dim3(BB * 5, 64), dim3(256), 0, stream, hist, trans, bp);
    hipLaunchKernelGGL(viterbi_btr, dim3(BB), dim3(64), 0, stream, hist, trans, bp, out_score, out_path);
}